// Round 15
// baseline (460.027 us; speedup 1.0000x reference)
//
#include <hip/hip_runtime.h>
#include <cstdint>

// ---------------------------------------------------------------------------
// GCN twin-tower forward. Round 15: quarter-split gather.
//   8 XCD groups = 2 towers x 4 feature-quarters. Per-XCD working set
//   6.4 -> 3.2MB (fits 4MB L2) -> random reads become L2 hits; compulsory
//   cross-fetch 51 -> 25.6MB. 4 threads/node x f16x8 (32 feat, 64B/row = one
//   cache line). Rest unchanged from round 14.
// ---------------------------------------------------------------------------

typedef _Float16 f16;
typedef f16 f16x8 __attribute__((ext_vector_type(8)));
typedef f16 f16x4 __attribute__((ext_vector_type(4)));
typedef float f32x4 __attribute__((ext_vector_type(4)));
typedef unsigned short u16;
typedef unsigned int u32;

#define CH 8192   // edges per chunk
#define BSH 8     // bucket shift: 256 nodes per bucket

// ---------------- BN stats: per-feature sum / sumsq, z = tower -------------
__global__ __launch_bounds__(256) void bn_stats_k(
    const float* __restrict__ x0, const float* __restrict__ x1,
    float* __restrict__ bnsum, float* __restrict__ bnsq, int n) {
  const float* x = blockIdx.z ? x1 : x0;
  float* bs = bnsum + blockIdx.z * 64;
  float* bq = bnsq + blockIdx.z * 64;
  __shared__ float ls[256], lq[256];
  const int tid = threadIdx.x;
  const int f = tid & 63;
  const int rb = tid >> 6;
  float s = 0.f, q = 0.f;
  for (int r = blockIdx.x * 4 + rb; r < n; r += gridDim.x * 4) {
    float v = x[(size_t)r * 64 + f];
    s += v;
    q += v * v;
  }
  ls[tid] = s;
  lq[tid] = q;
  __syncthreads();
  if (tid < 64) {
    s = ls[tid] + ls[tid + 64] + ls[tid + 128] + ls[tid + 192];
    q = lq[tid] + lq[tid + 64] + lq[tid + 128] + lq[tid + 192];
    atomicAdd(&bs[tid], s);
    atomicAdd(&bq[tid], q);
  }
}

// ------------- Fold BN affine into W1/b1, grid(2): x = tower ---------------
__global__ __launch_bounds__(256) void bn_fold_k(
    const float* __restrict__ bnsum, const float* __restrict__ bnsq,
    const float* __restrict__ gamma, const float* __restrict__ beta,
    const float* __restrict__ W1, const float* __restrict__ b1,
    float* __restrict__ W1f, float* __restrict__ b1f, float inv_n) {
  const int z = blockIdx.x;
  const float* bs = bnsum + z * 64;
  const float* bq = bnsq + z * 64;
  float* w1f = W1f + z * 16384;
  float* bf1 = b1f + z * 256;
  __shared__ float a[64], bf[64];
  const int tid = threadIdx.x;
  if (tid < 64) {
    float mu = bs[tid] * inv_n;
    float var = bq[tid] * inv_n - mu * mu;
    float s = gamma[tid] * rsqrtf(var + 1e-5f);
    a[tid] = s;
    bf[tid] = beta[tid] - mu * s;
  }
  __syncthreads();
  float acc = 0.f;
#pragma unroll
  for (int f = 0; f < 64; ++f) {
    float w = W1[f * 256 + tid];
    w1f[f * 256 + tid] = a[f] * w;
    acc += bf[f] * w;
  }
  bf1[tid] = b1[tid] + acc;
}

// ---- transpose + fp16-split: W[K][N] f32 -> Wt[N][K] f16, z-strided -------
__global__ __launch_bounds__(256) void wtrans_k(
    const float* __restrict__ W, int sstride, f16* __restrict__ Wth,
    f16* __restrict__ Wtl, int dstride, int K, int N) {
  const int z = blockIdx.z;
  const float* Wp = W + (size_t)z * sstride;
  f16* th = Wth + (size_t)z * dstride;
  f16* tl = Wtl + (size_t)z * dstride;
  int n = blockIdx.x * 64 + (threadIdx.x & 63);
  int k = blockIdx.y * 4 + (threadIdx.x >> 6);
  float v = Wp[(size_t)k * N + n];
  f16 h = (f16)v;
  f16 l = (f16)(v - (float)h);
  th[(size_t)n * K + k] = h;
  tl[(size_t)n * K + k] = l;
}

// one dispatch for all 6 static weights; z = weight id, masked by shape
__global__ __launch_bounds__(256) void wtrans_all_k(
    const float* __restrict__ W2, const float* __restrict__ Wc0,
    const float* __restrict__ Wc1, const float* __restrict__ Wc2,
    const float* __restrict__ W3, const float* __restrict__ W4,
    f16* __restrict__ t2h, f16* __restrict__ t2l, f16* __restrict__ tc0h,
    f16* __restrict__ tc0l, f16* __restrict__ tc1h, f16* __restrict__ tc1l,
    f16* __restrict__ tc2h, f16* __restrict__ tc2l, f16* __restrict__ t3h,
    f16* __restrict__ t3l, f16* __restrict__ t4h, f16* __restrict__ t4l) {
  const int w = blockIdx.z;
  const float* Wp;
  f16 *th, *tl;
  int K, N;
  switch (w) {
    case 0: Wp = W2;  th = t2h;  tl = t2l;  K = 256; N = 128; break;
    case 1: Wp = Wc0; th = tc0h; tl = tc0l; K = 128; N = 128; break;
    case 2: Wp = Wc1; th = tc1h; tl = tc1l; K = 128; N = 128; break;
    case 3: Wp = Wc2; th = tc2h; tl = tc2l; K = 128; N = 128; break;
    case 4: Wp = W3;  th = t3h;  tl = t3l;  K = 256; N = 256; break;
    default: Wp = W4; th = t4h;  tl = t4l;  K = 256; N = 128; break;
  }
  int n = blockIdx.x * 64 + (threadIdx.x & 63);
  int k = blockIdx.y * 4 + (threadIdx.x >> 6);
  if (n >= N || k >= K) return;
  float v = Wp[(size_t)k * N + n];
  f16 h = (f16)v;
  f16 l = (f16)(v - (float)h);
  th[(size_t)n * K + k] = h;
  tl[(size_t)n * K + k] = l;
}

// ---------------- MFMA GEMM core ------------------------------------------
template <int AF16, int OUT16>
__device__ __forceinline__ void gemm_core(
    const void* __restrict__ Av, const f16* __restrict__ Wth,
    const f16* __restrict__ Wtl, const float* __restrict__ bias,
    const float* __restrict__ rowscale, float* __restrict__ C,
    f16* __restrict__ C16, int M, int N, int K, int relu) {
  __shared__ f16 Ah[64][40];
  __shared__ f16 Al[AF16 ? 1 : 64][40];
  __shared__ f16 Bh[128][40], Bl[128][40];
  const int tid = threadIdx.x;
  const int wave = tid >> 6;
  const int lane = tid & 63;
  const int wm = wave & 1;
  const int wn = wave >> 1;
  const int l15 = lane & 15;
  const int lk8 = (lane >> 4) * 8;
  const int sam = tid >> 2;
  const int sak = (tid & 3) * 8;
  const int sbn = tid >> 1;
  const int sbk = (tid & 1) * 16;
  const int arow = blockIdx.y * 64 + sam;
  const f16* bhp = Wth + (size_t)(blockIdx.x * 128 + sbn) * K + sbk;
  const f16* blp = Wtl + (size_t)(blockIdx.x * 128 + sbn) * K + sbk;
  const float* aptr32 = nullptr;
  const f16* aptr16 = nullptr;
  if constexpr (AF16)
    aptr16 = (const f16*)Av + (size_t)arow * K + sak;
  else
    aptr32 = (const float*)Av + (size_t)arow * K + sak;

  f32x4 acc[2][4];
#pragma unroll
  for (int mi = 0; mi < 2; ++mi)
#pragma unroll
    for (int ni = 0; ni < 4; ++ni) acc[mi][ni] = (f32x4){0.f, 0.f, 0.f, 0.f};

  float4 pa0, pa1;
  f16x8 pa16 = {0, 0, 0, 0, 0, 0, 0, 0};
  if constexpr (AF16) {
    if (arow < M) pa16 = *(const f16x8*)aptr16;
  } else {
    if (arow < M) {
      pa0 = *(const float4*)aptr32;
      pa1 = *(const float4*)(aptr32 + 4);
    } else {
      pa0 = make_float4(0.f, 0.f, 0.f, 0.f);
      pa1 = pa0;
    }
  }
  f16x8 pbh0 = *(const f16x8*)bhp;
  f16x8 pbh1 = *(const f16x8*)(bhp + 8);
  f16x8 pbl0 = *(const f16x8*)blp;
  f16x8 pbl1 = *(const f16x8*)(blp + 8);

  const int nk = K / 32;
  for (int t = 0; t < nk; ++t) {
    if (t) __syncthreads();
    if constexpr (AF16) {
      *(f16x8*)&Ah[sam][sak] = pa16;
    } else {
      float av[8] = {pa0.x, pa0.y, pa0.z, pa0.w, pa1.x, pa1.y, pa1.z, pa1.w};
      f16x8 vh, vl;
#pragma unroll
      for (int j = 0; j < 8; ++j) {
        f16 h = (f16)av[j];
        vh[j] = h;
        vl[j] = (f16)(av[j] - (float)h);
      }
      *(f16x8*)&Ah[sam][sak] = vh;
      *(f16x8*)&Al[sam][sak] = vl;
    }
    *(f16x8*)&Bh[sbn][sbk] = pbh0;
    *(f16x8*)&Bh[sbn][sbk + 8] = pbh1;
    *(f16x8*)&Bl[sbn][sbk] = pbl0;
    *(f16x8*)&Bl[sbn][sbk + 8] = pbl1;
    __syncthreads();
    if (t + 1 < nk) {
      const int k0 = (t + 1) * 32;
      if constexpr (AF16) {
        if (arow < M) pa16 = *(const f16x8*)(aptr16 + k0);
      } else {
        if (arow < M) {
          pa0 = *(const float4*)(aptr32 + k0);
          pa1 = *(const float4*)(aptr32 + k0 + 4);
        } else {
          pa0 = make_float4(0.f, 0.f, 0.f, 0.f);
          pa1 = pa0;
        }
      }
      pbh0 = *(const f16x8*)(bhp + k0);
      pbh1 = *(const f16x8*)(bhp + k0 + 8);
      pbl0 = *(const f16x8*)(blp + k0);
      pbl1 = *(const f16x8*)(blp + k0 + 8);
    }
    f16x8 ath[2], atl[2];
#pragma unroll
    for (int mi = 0; mi < 2; ++mi) {
      const int r = wm * 32 + mi * 16 + l15;
      ath[mi] = *(const f16x8*)&Ah[r][lk8];
      if constexpr (!AF16) atl[mi] = *(const f16x8*)&Al[r][lk8];
    }
    f16x8 bth[4], btl[4];
#pragma unroll
    for (int ni = 0; ni < 4; ++ni) {
      const int r = wn * 64 + ni * 16 + l15;
      bth[ni] = *(const f16x8*)&Bh[r][lk8];
      btl[ni] = *(const f16x8*)&Bl[r][lk8];
    }
#pragma unroll
    for (int mi = 0; mi < 2; ++mi)
#pragma unroll
      for (int ni = 0; ni < 4; ++ni) {
        acc[mi][ni] = __builtin_amdgcn_mfma_f32_16x16x32_f16(
            bth[ni], ath[mi], acc[mi][ni], 0, 0, 0);
        acc[mi][ni] = __builtin_amdgcn_mfma_f32_16x16x32_f16(
            btl[ni], ath[mi], acc[mi][ni], 0, 0, 0);
        if constexpr (!AF16)
          acc[mi][ni] = __builtin_amdgcn_mfma_f32_16x16x32_f16(
              bth[ni], atl[mi], acc[mi][ni], 0, 0, 0);
      }
  }

#pragma unroll
  for (int mi = 0; mi < 2; ++mi) {
    const int m = blockIdx.y * 64 + wm * 32 + mi * 16 + l15;
    if (m >= M) continue;
    float s = 1.f;
    if (OUT16 && rowscale) s = rowscale[m];
#pragma unroll
    for (int ni = 0; ni < 4; ++ni) {
      const int nb = blockIdx.x * 128 + wn * 64 + ni * 16 + (lane >> 4) * 4;
      float bv[4] = {0.f, 0.f, 0.f, 0.f};
      if (bias) {
        float4 b4 = *(const float4*)(bias + nb);
        bv[0] = b4.x; bv[1] = b4.y; bv[2] = b4.z; bv[3] = b4.w;
      }
      if constexpr (OUT16) {
        f16x4 h;
#pragma unroll
        for (int j = 0; j < 4; ++j) {
          float vj = acc[mi][ni][j] * s + bv[j];
          if (relu) vj = fmaxf(vj, 0.f);
          h[j] = (f16)vj;
        }
        *(f16x4*)(C16 + (size_t)m * N + nb) = h;
      } else {
        float4 v;
        v.x = acc[mi][ni][0] + bv[0];
        v.y = acc[mi][ni][1] + bv[1];
        v.z = acc[mi][ni][2] + bv[2];
        v.w = acc[mi][ni][3] + bv[3];
        if (relu) {
          v.x = fmaxf(v.x, 0.f);
          v.y = fmaxf(v.y, 0.f);
          v.z = fmaxf(v.z, 0.f);
          v.w = fmaxf(v.w, 0.f);
        }
        *(float4*)(C + (size_t)m * N + nb) = v;
      }
    }
  }
}

__global__ __launch_bounds__(256) void gemm_a32_f16o(
    const float* __restrict__ A0, const float* __restrict__ A1,
    const f16* __restrict__ Wth0, const f16* __restrict__ Wth1,
    const f16* __restrict__ Wtl0, const f16* __restrict__ Wtl1,
    const float* __restrict__ bias0, const float* __restrict__ bias1,
    f16* __restrict__ C0, f16* __restrict__ C1, int M, int N, int K,
    int relu) {
  const int z = blockIdx.z;
  gemm_core<0, 1>(z ? A1 : A0, z ? Wth1 : Wth0, z ? Wtl1 : Wtl0,
                  z ? bias1 : bias0, nullptr, nullptr, z ? C1 : C0, M, N, K,
                  relu);
}

__global__ __launch_bounds__(256) void gemm_a16_f16o(
    const f16* __restrict__ A0, const f16* __restrict__ A1,
    const f16* __restrict__ Wth, const f16* __restrict__ Wtl,
    const float* __restrict__ bias, const float* __restrict__ rowscale,
    f16* __restrict__ C0, f16* __restrict__ C1, int M, int N, int K,
    int relu) {
  const int z = blockIdx.z;
  gemm_core<1, 1>(z ? A1 : A0, Wth, Wtl, bias,
                  rowscale ? rowscale + (size_t)z * M : nullptr, nullptr,
                  z ? C1 : C0, M, N, K, relu);
}

__global__ __launch_bounds__(256) void gemm_a32_f32o(
    const float* __restrict__ A, const f16* __restrict__ Wth,
    const f16* __restrict__ Wtl, const float* __restrict__ bias,
    float* __restrict__ C, int M, int N, int K, int relu) {
  gemm_core<0, 0>(A, Wth, Wtl, bias, nullptr, C, nullptr, M, N, K, relu);
}

// ============== CSR build: deterministic two-level counting sort ===========
__global__ __launch_bounds__(256) void hist_k(
    const int* __restrict__ ei0, const int* __restrict__ ei1,
    int* __restrict__ ghist, int e, int nbkt, int nc) {
  const int z = blockIdx.z;
  const int c = blockIdx.x;
  const int* dst = (z ? ei1 : ei0) + e;
  int* gh = ghist + (size_t)z * nbkt * nc;
  __shared__ int h[256];
  h[threadIdx.x] = 0;
  __syncthreads();
  const int i0 = c * CH;
  const int i1 = min(e, i0 + CH);
  for (int i = i0 + threadIdx.x; i < i1; i += 256)
    atomicAdd(&h[__builtin_nontemporal_load(dst + i) >> BSH], 1);
  __syncthreads();
  if (threadIdx.x < nbkt) gh[threadIdx.x * nc + c] = h[threadIdx.x];
}

__global__ __launch_bounds__(1024) void scanh_k(int* __restrict__ ghist,
                                                int nbkt, int nc) {
  const int tot = nbkt * nc;
  int* gh = ghist + (size_t)blockIdx.z * tot;
  __shared__ int part[1024];
  const int t = threadIdx.x;
  const int per = (tot + 1023) / 1024;
  const int base = t * per;
  int s = 0;
  for (int j = 0; j < per; ++j) {
    int i = base + j;
    if (i < tot) s += gh[i];
  }
  part[t] = s;
  __syncthreads();
  for (int off = 1; off < 1024; off <<= 1) {
    int v = (t >= off) ? part[t - off] : 0;
    __syncthreads();
    part[t] += v;
    __syncthreads();
  }
  int run = part[t] - s;  // exclusive prefix
  for (int j = 0; j < per; ++j) {
    int i = base + j;
    if (i < tot) {
      int v = gh[i];
      gh[i] = run;
      run += v;
    }
  }
}

__global__ __launch_bounds__(256) void scatter_k(
    const int* __restrict__ ei0, const int* __restrict__ ei1,
    const int* __restrict__ ghist, u32* __restrict__ ebkt, int e, int nbkt,
    int nc) {
  const int z = blockIdx.z;
  const int c = blockIdx.x;
  const int* src = z ? ei1 : ei0;
  const int* dst = src + e;
  const int* gh = ghist + (size_t)z * nbkt * nc;
  u32* eb = ebkt + (size_t)z * e;
  __shared__ int cur[256];
  if (threadIdx.x < nbkt) cur[threadIdx.x] = gh[threadIdx.x * nc + c];
  __syncthreads();
  const int i0 = c * CH;
  const int i1 = min(e, i0 + CH);
  for (int i = i0 + threadIdx.x; i < i1; i += 256) {
    int s = __builtin_nontemporal_load(src + i);
    int d = __builtin_nontemporal_load(dst + i);
    int pos = atomicAdd(&cur[d >> BSH], 1);
    eb[pos] = (u32)s | ((u32)(d & 255) << 16);
  }
}

__global__ __launch_bounds__(256) void build_k(
    const int* __restrict__ ghist, const u32* __restrict__ ebkt,
    u16* __restrict__ esrc, int* __restrict__ rowstart,
    float* __restrict__ dinv, int e, int n, int nbkt, int nc) {
  const int z = blockIdx.z;
  const int b = blockIdx.x;
  const int* gh = ghist + (size_t)z * nbkt * nc;
  const u32* eb = ebkt + (size_t)z * e;
  u16* es = esrc + (size_t)z * e;
  int* rs = rowstart + (size_t)z * (n + 1);
  float* dv = dinv + (size_t)z * n;
  const int tid = threadIdx.x;
  const int bstart = gh[b * nc];
  const int bend = (b + 1 < nbkt) ? gh[(b + 1) * nc] : e;
  const int cnt = bend - bstart;
  __shared__ int h[256], ts[256], cur[256];
  __shared__ u16 stage[12288];
  h[tid] = 0;
  __syncthreads();
  for (int i = bstart + tid; i < bend; i += 256)
    atomicAdd(&h[eb[i] >> 16], 1);
  __syncthreads();
  int deg = h[tid];
  ts[tid] = deg;
  __syncthreads();
  for (int off = 1; off < 256; off <<= 1) {
    int v = (tid >= off) ? ts[tid - off] : 0;
    __syncthreads();
    ts[tid] += v;
    __syncthreads();
  }
  const int excl = ts[tid] - deg;
  const int vglob = (b << BSH) + tid;
  if (vglob <= n) rs[vglob] = bstart + excl;
  if (vglob < n) dv[vglob] = rsqrtf((float)(deg + 1));
  cur[tid] = excl;
  __syncthreads();
  if (cnt <= 12288) {
    for (int i = bstart + tid; i < bend; i += 256) {
      u32 p = eb[i];
      int pos = atomicAdd(&cur[p >> 16], 1);
      stage[pos] = (u16)(p & 0xffff);
    }
    __syncthreads();
    for (int j = tid; j < cnt; j += 256) es[bstart + j] = stage[j];
  } else {
    for (int i = bstart + tid; i < bend; i += 256) {
      u32 p = eb[i];
      int pos = atomicAdd(&cur[p >> 16], 1);
      es[bstart + pos] = (u16)(p & 0xffff);
    }
  }
}

// -------- gather: quarter-split, x8-unrolled, XCD-partitioned --------------
// 1D grid; group = blk&7 = (tower<<2)|quarter, idx = blk>>3.
// 4 threads/node x f16x8 (32 features). Per-XCD working set 3.2MB (< L2).
__global__ __launch_bounds__(256) void gather4_k(
    const int* __restrict__ rowstart, const u16* __restrict__ esrc,
    const f16* __restrict__ xw16, const float* __restrict__ dinv,
    const float* __restrict__ bias, f16* __restrict__ out0,
    f16* __restrict__ out1, int n, int e) {
  const int blk = blockIdx.x;
  const int grp = blk & 7;
  const int z = grp >> 2;
  const int quarter = grp & 3;
  const int idx = blk >> 3;
  const int* rs = rowstart + (size_t)z * (n + 1);
  const u16* es = esrc + (size_t)z * e;
  const f16x8* x8 = (const f16x8*)(xw16 + (size_t)z * n * 128);
  const float* dv = dinv + (size_t)z * n;
  f16* out = z ? out1 : out0;
  int gid = idx * 256 + threadIdx.x;
  int v = gid >> 2;
  if (v >= n) return;
  int q = gid & 3;
  const int fo = quarter * 4 + q;  // f16x8 index within row (16 per row)
  f16x8 sv = x8[(size_t)v * 16 + fo];
  float acc[8];
#pragma unroll
  for (int j = 0; j < 8; ++j) acc[j] = (float)sv[j];
  const int s0 = rs[v], s1 = rs[v + 1];
  int ed = s0;
  for (; ed + 8 <= s1; ed += 8) {
    int si[8];
#pragma unroll
    for (int u = 0; u < 8; ++u) si[u] = es[ed + u];
    f16x8 t[8];
#pragma unroll
    for (int u = 0; u < 8; ++u) t[u] = x8[(size_t)si[u] * 16 + fo];
#pragma unroll
    for (int j = 0; j < 8; ++j)
      acc[j] += (((float)t[0][j] + (float)t[1][j]) +
                 ((float)t[2][j] + (float)t[3][j])) +
                (((float)t[4][j] + (float)t[5][j]) +
                 ((float)t[6][j] + (float)t[7][j]));
  }
  for (; ed + 4 <= s1; ed += 4) {
    int sa = es[ed], sb = es[ed + 1], sc = es[ed + 2], sd = es[ed + 3];
    f16x8 ta = x8[(size_t)sa * 16 + fo];
    f16x8 tb = x8[(size_t)sb * 16 + fo];
    f16x8 tc = x8[(size_t)sc * 16 + fo];
    f16x8 td = x8[(size_t)sd * 16 + fo];
#pragma unroll
    for (int j = 0; j < 8; ++j)
      acc[j] += ((float)ta[j] + (float)tb[j]) + ((float)tc[j] + (float)td[j]);
  }
  for (; ed < s1; ++ed) {
    f16x8 t = x8[(size_t)es[ed] * 16 + fo];
#pragma unroll
    for (int j = 0; j < 8; ++j) acc[j] += (float)t[j];
  }
  float d = dv[v];
  float4 b0 = *(const float4*)(bias + fo * 8);
  float4 b1 = *(const float4*)(bias + fo * 8 + 4);
  float bb[8] = {b0.x, b0.y, b0.z, b0.w, b1.x, b1.y, b1.z, b1.w};
  f16x8 o;
#pragma unroll
  for (int j = 0; j < 8; ++j) o[j] = (f16)fmaxf(acc[j] * d + bb[j], 0.f);
  *(f16x8*)(out + (size_t)v * 128 + fo * 8) = o;
}

// ---------------- pool: segmented mean (f16 in, f32 out), z = tower --------
__global__ __launch_bounds__(256) void bstart_k(const int* __restrict__ b0,
                                                const int* __restrict__ b1,
                                                int* __restrict__ bstart,
                                                int n, int nb) {
  const int z = blockIdx.z;
  const int* batch = z ? b1 : b0;
  int* bst = bstart + (size_t)z * (nb + 1);
  int b = blockIdx.x * 256 + threadIdx.x;
  if (b > nb) return;
  int lo = 0, hi = n;
  while (lo < hi) {
    int mid = (lo + hi) >> 1;
    if (batch[mid] < b) lo = mid + 1; else hi = mid;
  }
  bst[b] = lo;
}

__global__ __launch_bounds__(128) void pool_seg_k(
    const f16* __restrict__ h0, const f16* __restrict__ h1,
    const int* __restrict__ bstart, float* __restrict__ cat, int nb) {
  const int z = blockIdx.z;
  const f16* h = z ? h1 : h0;
  const int* bst = bstart + (size_t)z * (nb + 1);
  int b = blockIdx.x;
  int s = bst[b], e = bst[b + 1];
  int f = threadIdx.x;
  float acc = 0.f;
  for (int v = s; v < e; ++v) acc += (float)h[(size_t)v * 128 + f];
  float c = fmaxf((float)(e - s), 1.f);
  cat[(size_t)b * 256 + z * 128 + f] = acc / c;
}

// ---------------- final: out[r] = z2[r,:]@W5 + b5 --------------------------
__global__ __launch_bounds__(256) void final_k(const float* __restrict__ z2,
                                               const float* __restrict__ W5,
                                               const float* __restrict__ b5,
                                               float* __restrict__ out,
                                               int rows) {
  int r = blockIdx.x * 256 + threadIdx.x;
  if (r >= rows) return;
  float acc = b5[0];
#pragma unroll
  for (int k = 0; k < 128; ++k) acc += z2[(size_t)r * 128 + k] * W5[k];
  out[r] = acc;
}

// ---------------------------------------------------------------------------
extern "C" void kernel_launch(void* const* d_in, const int* in_sizes, int n_in,
                              void* d_out, int out_size, void* d_ws,
                              size_t ws_size, hipStream_t stream) {
  const float* x0 = (const float*)d_in[0];
  const float* x1 = (const float*)d_in[3];
  const int* ei0 = (const int*)d_in[1];
  const int* ei1 = (const int*)d_in[4];
  const int* ba0 = (const int*)d_in[2];
  const int* ba1 = (const int*)d_in[5];
  const float* gamma = (const float*)d_in[6];
  const float* beta = (const float*)d_in[7];
  const float* W1 = (const float*)d_in[8];
  const float* b1 = (const float*)d_in[9];
  const float* W2 = (const float*)d_in[10];
  const float* b2 = (const float*)d_in[11];
  const float* Wc[3] = {(const float*)d_in[12], (const float*)d_in[14],
                        (const float*)d_in[16]};
  const float* bc[3] = {(const float*)d_in[13], (const float*)d_in[15],
                        (const float*)d_in[17]};
  const float* W3 = (const float*)d_in[18];
  const float* b3 = (const float*)d_in[19];
  const float* W4 = (const float*)d_in[20];
  const float* b4 = (const float*)d_in[21];
  const float* W5 = (const float*)d_in[22];
  const float* b5 = (const float*)d_in[23];
  float* out = (float*)d_out;

  const int N = in_sizes[0] / 64;  // 50000
  const int E = in_sizes[1] / 2;   // 600000
  const int B = out_size;          // 512
  const int NBKT = (N + 255) >> BSH;       // 196
  const int NC = (E + CH - 1) / CH;        // 74

  // ---- workspace layout (f16 activations, both towers resident) ----
  f16* fp = (f16*)d_ws;
  f16* h0_16 = fp; fp += (size_t)2 * N * 256;  // GEMM1 out
  f16* hA16 = fp; fp += (size_t)2 * N * 128;   // activation ping
  f16* hB16 = fp; fp += (size_t)2 * N * 128;   // activation pong
  f16* xw16 = fp; fp += (size_t)2 * N * 128;   // conv GEMM out (dinv-scaled)
  float* dinv = (float*)fp;                    // 2*N
  u16* esrc = (u16*)(dinv + (size_t)2 * N);    // 2*E
  u32* ebkt = (u32*)(esrc + (size_t)2 * E);    // 2*E u32
  int* ghist = (int*)(ebkt + (size_t)2 * E);   // 2*NBKT*NC
  int* rowstart = ghist + (size_t)2 * NBKT * NC;  // 2*(N+1)
  int* bstart = rowstart + (size_t)2 * (N + 1);   // 2*(B+1)
  float* bnsum = (float*)(bstart + 2 * (B + 1));  // 128
  float* bnsq = bnsum + 128;
  float* W1f = bnsq + 128;                     // 2*16384
  float* b1f = W1f + 2 * 16384;                // 512
  float* catb = b1f + 512;                     // B*256
  float* z1 = catb + (size_t)B * 256;          // B*256
  float* z2 = z1 + (size_t)B * 256;            // B*128
  f16* wtp = (f16*)(((uintptr_t)(z2 + (size_t)B * 128) + 63) &
                    ~(uintptr_t)63);
  f16* w1t_h = wtp; wtp += 2 * 16384;
  f16* w1t_l = wtp; wtp += 2 * 16384;
  f16* w2t_h = wtp; wtp += 32768;
  f16* w2t_l = wtp; wtp += 32768;
  f16* wct_h[3]; f16* wct_l[3];
  for (int c = 0; c < 3; ++c) {
    wct_h[c] = wtp; wtp += 16384;
    wct_l[c] = wtp; wtp += 16384;
  }
  f16* w3t_h = wtp; wtp += 65536;
  f16* w3t_l = wtp; wtp += 65536;
  f16* w4t_h = wtp; wtp += 32768;
  f16* w4t_l = wtp; wtp += 32768;
  size_t need = (size_t)((char*)wtp - (char*)d_ws);
  if (ws_size < need) return;

  f16* h0_[2] = {h0_16, h0_16 + (size_t)N * 256};
  f16* hA_[2] = {hA16, hA16 + (size_t)N * 128};
  f16* hB_[2] = {hB16, hB16 + (size_t)N * 128};

  const int nb_g4 = (N * 4 + 255) / 256;  // gather blocks per group (782)
  const int g_grid = nb_g4 * 8;           // 8 XCD groups
  const int gby = (N + 63) / 64;          // 782

  hipMemsetAsync(bnsum, 0, 256 * sizeof(float), stream);

  // ---- shared weights: transpose+split, ONE dispatch ----
  wtrans_all_k<<<dim3(4, 64, 6), 256, 0, stream>>>(
      W2, Wc[0], Wc[1], Wc[2], W3, W4, w2t_h, w2t_l, wct_h[0], wct_l[0],
      wct_h[1], wct_l[1], wct_h[2], wct_l[2], w3t_h, w3t_l, w4t_h, w4t_l);

  // ---- BN -> folded W1 (per tower) ----
  bn_stats_k<<<dim3(256, 1, 2), 256, 0, stream>>>(x0, x1, bnsum, bnsq, N);
  bn_fold_k<<<2, 256, 0, stream>>>(bnsum, bnsq, gamma, beta, W1, b1, W1f, b1f,
                                   1.0f / (float)N);
  wtrans_k<<<dim3(4, 16, 2), 256, 0, stream>>>(W1f, 16384, w1t_h, w1t_l,
                                               16384, 64, 256);

  // ---- dense head of each tower (f16 chain) ----
  gemm_a32_f16o<<<dim3(2, gby, 2), 256, 0, stream>>>(
      x0, x1, w1t_h, w1t_h + 16384, w1t_l, w1t_l + 16384, b1f, b1f + 256,
      h0_[0], h0_[1], N, 256, 64, 1);
  gemm_a16_f16o<<<dim3(1, gby, 2), 256, 0, stream>>>(
      h0_[0], h0_[1], w2t_h, w2t_l, b2, nullptr, hA_[0], hA_[1], N, 128, 256,
      1);

  // ---- CSR build: two-level counting sort (deterministic) ----
  hist_k<<<dim3(NC, 1, 2), 256, 0, stream>>>(ei0, ei1, ghist, E, NBKT, NC);
  scanh_k<<<dim3(1, 1, 2), 1024, 0, stream>>>(ghist, NBKT, NC);
  scatter_k<<<dim3(NC, 1, 2), 256, 0, stream>>>(ei0, ei1, ghist, ebkt, E,
                                                NBKT, NC);
  build_k<<<dim3(NBKT, 1, 2), 256, 0, stream>>>(ghist, ebkt, esrc, rowstart,
                                                dinv, E, N, NBKT, NC);
  bstart_k<<<dim3((B + 256) / 256, 1, 2), 256, 0, stream>>>(ba0, ba1, bstart,
                                                            N, B);

  // ---- 3 conv layers: GEMM(f16, dinv-scaled) + gather (f16 out) ----
  f16* cin[3][2] = {{hA_[0], hA_[1]}, {hB_[0], hB_[1]}, {hA_[0], hA_[1]}};
  f16* cout[3][2] = {{hB_[0], hB_[1]}, {hA_[0], hA_[1]}, {hB_[0], hB_[1]}};
  for (int c = 0; c < 3; ++c) {
    gemm_a16_f16o<<<dim3(1, gby, 2), 256, 0, stream>>>(
        cin[c][0], cin[c][1], wct_h[c], wct_l[c], nullptr, dinv, xw16,
        xw16 + (size_t)N * 128, N, 128, 128, 0);
    gather4_k<<<dim3(g_grid, 1, 1), 256, 0, stream>>>(
        rowstart, esrc, xw16, dinv, bc[c], cout[c][0], cout[c][1], N, E);
  }

  // ---- pool (both towers) ----
  pool_seg_k<<<dim3(B, 1, 2), 128, 0, stream>>>(hB_[0], hB_[1], bstart, catb,
                                                B);

  // ---- head MLP (f32) ----
  gemm_a32_f32o<<<dim3(2, (B + 63) / 64, 1), 256, 0, stream>>>(
      catb, w3t_h, w3t_l, b3, z1, B, 256, 256, 1);
  gemm_a32_f32o<<<dim3(1, (B + 63) / 64, 1), 256, 0, stream>>>(
      z1, w4t_h, w4t_l, b4, z2, B, 128, 256, 1);
  final_k<<<(B + 255) / 256, 256, 0, stream>>>(z2, W5, b5, out, B);
}

// Round 16
// 409.401 us; speedup vs baseline: 1.1237x; 1.1237x over previous
//
#include <hip/hip_runtime.h>
#include <cstdint>

// ---------------------------------------------------------------------------
// GCN twin-tower forward. Round 16:
//   - REVERT gather to round-14 half-split gather8_k (quarter-split's 64B
//     slices caused 2x line over-fetch: FETCH 81->157MB regression).
//   - fused12_k: GEMM1+GEMM2 in one kernel. Phase 1 computes h0 half
//     (64x128) into LDS, phase 2 accumulates h0@W2 partial-K immediately.
//     Saves 102MB h0 round-trip + a dispatch. Numerics = round 14.
//   - bn_fold writes transposed/split w1t directly (drops W1f + wtrans).
// ---------------------------------------------------------------------------

typedef _Float16 f16;
typedef f16 f16x8 __attribute__((ext_vector_type(8)));
typedef f16 f16x4 __attribute__((ext_vector_type(4)));
typedef float f32x4 __attribute__((ext_vector_type(4)));
typedef unsigned short u16;
typedef unsigned int u32;

#define CH 8192   // edges per chunk
#define BSH 8     // bucket shift: 256 nodes per bucket

// ---------------- BN stats: per-feature sum / sumsq, z = tower -------------
__global__ __launch_bounds__(256) void bn_stats_k(
    const float* __restrict__ x0, const float* __restrict__ x1,
    float* __restrict__ bnsum, float* __restrict__ bnsq, int n) {
  const float* x = blockIdx.z ? x1 : x0;
  float* bs = bnsum + blockIdx.z * 64;
  float* bq = bnsq + blockIdx.z * 64;
  __shared__ float ls[256], lq[256];
  const int tid = threadIdx.x;
  const int f = tid & 63;
  const int rb = tid >> 6;
  float s = 0.f, q = 0.f;
  for (int r = blockIdx.x * 4 + rb; r < n; r += gridDim.x * 4) {
    float v = x[(size_t)r * 64 + f];
    s += v;
    q += v * v;
  }
  ls[tid] = s;
  lq[tid] = q;
  __syncthreads();
  if (tid < 64) {
    s = ls[tid] + ls[tid + 64] + ls[tid + 128] + ls[tid + 192];
    q = lq[tid] + lq[tid + 64] + lq[tid + 128] + lq[tid + 192];
    atomicAdd(&bs[tid], s);
    atomicAdd(&bq[tid], q);
  }
}

// --- Fold BN into W1: write transposed+split w1t [256][64] f16 directly ----
__global__ __launch_bounds__(256) void bn_fold_k(
    const float* __restrict__ bnsum, const float* __restrict__ bnsq,
    const float* __restrict__ gamma, const float* __restrict__ beta,
    const float* __restrict__ W1, const float* __restrict__ b1,
    f16* __restrict__ w1th, f16* __restrict__ w1tl, float* __restrict__ b1f,
    float inv_n) {
  const int z = blockIdx.x;
  const float* bs = bnsum + z * 64;
  const float* bq = bnsq + z * 64;
  f16* th = w1th + (size_t)z * 16384;
  f16* tl = w1tl + (size_t)z * 16384;
  float* bf1 = b1f + z * 256;
  __shared__ float a[64], bf[64];
  const int tid = threadIdx.x;
  if (tid < 64) {
    float mu = bs[tid] * inv_n;
    float var = bq[tid] * inv_n - mu * mu;
    float s = gamma[tid] * rsqrtf(var + 1e-5f);
    a[tid] = s;
    bf[tid] = beta[tid] - mu * s;
  }
  __syncthreads();
  float acc = 0.f;
#pragma unroll
  for (int f = 0; f < 64; ++f) {
    float w = W1[f * 256 + tid];
    float v = a[f] * w;
    f16 hh = (f16)v;
    th[(size_t)tid * 64 + f] = hh;
    tl[(size_t)tid * 64 + f] = (f16)(v - (float)hh);
    acc += bf[f] * w;
  }
  bf1[tid] = b1[tid] + acc;
}

// one dispatch for all 6 static weights; z = weight id, masked by shape
__global__ __launch_bounds__(256) void wtrans_all_k(
    const float* __restrict__ W2, const float* __restrict__ Wc0,
    const float* __restrict__ Wc1, const float* __restrict__ Wc2,
    const float* __restrict__ W3, const float* __restrict__ W4,
    f16* __restrict__ t2h, f16* __restrict__ t2l, f16* __restrict__ tc0h,
    f16* __restrict__ tc0l, f16* __restrict__ tc1h, f16* __restrict__ tc1l,
    f16* __restrict__ tc2h, f16* __restrict__ tc2l, f16* __restrict__ t3h,
    f16* __restrict__ t3l, f16* __restrict__ t4h, f16* __restrict__ t4l) {
  const int w = blockIdx.z;
  const float* Wp;
  f16 *th, *tl;
  int K, N;
  switch (w) {
    case 0: Wp = W2;  th = t2h;  tl = t2l;  K = 256; N = 128; break;
    case 1: Wp = Wc0; th = tc0h; tl = tc0l; K = 128; N = 128; break;
    case 2: Wp = Wc1; th = tc1h; tl = tc1l; K = 128; N = 128; break;
    case 3: Wp = Wc2; th = tc2h; tl = tc2l; K = 128; N = 128; break;
    case 4: Wp = W3;  th = t3h;  tl = t3l;  K = 256; N = 256; break;
    default: Wp = W4; th = t4h;  tl = t4l;  K = 256; N = 128; break;
  }
  int n = blockIdx.x * 64 + (threadIdx.x & 63);
  int k = blockIdx.y * 4 + (threadIdx.x >> 6);
  if (n >= N || k >= K) return;
  float v = Wp[(size_t)k * N + n];
  f16 h = (f16)v;
  f16 l = (f16)(v - (float)h);
  th[(size_t)n * K + k] = h;
  tl[(size_t)n * K + k] = l;
}

// ---------------- fused GEMM1+GEMM2: hA = relu(relu(x@W1f+b1)@W2+b2) -------
// 64-row tile, 256 thr = 4 waves (2m x 2n). Phase 1 per 128-col half into
// LDS H[64][136]; phase 2 accumulates that half's K immediately.
__global__ __launch_bounds__(256) void fused12_k(
    const float* __restrict__ x0, const float* __restrict__ x1,
    const f16* __restrict__ w1th, const f16* __restrict__ w1tl,
    const float* __restrict__ b1f, const f16* __restrict__ w2th,
    const f16* __restrict__ w2tl, const float* __restrict__ b2,
    f16* __restrict__ hA0, f16* __restrict__ hA1, int M) {
  const int z = blockIdx.z;
  const float* x = z ? x1 : x0;
  const f16* W1h = w1th + (size_t)z * 16384;
  const f16* W1l = w1tl + (size_t)z * 16384;
  const float* bb1 = b1f + z * 256;
  f16* out = z ? hA1 : hA0;
  __shared__ f16 Ah[64][72], Al[64][72];   // x tile, K=64, split
  __shared__ f16 Bh[128][40], Bl[128][40]; // weight K-chunk (32)
  __shared__ f16 H[64][136];               // h0 half tile [m][k-local]
  const int tid = threadIdx.x;
  const int wave = tid >> 6;
  const int lane = tid & 63;
  const int wm = wave & 1;
  const int wn = wave >> 1;
  const int l15 = lane & 15;
  const int lk8 = (lane >> 4) * 8;
  const int sbn = tid >> 1;        // B stage row (n)
  const int sbk = (tid & 1) * 16;  // B stage k offset
  // ---- stage x tile once (64 x 64 f32 -> f16 hi/lo) ----
  {
    const int sam = tid >> 2, sak = (tid & 3) * 16;
    const int arow = blockIdx.y * 64 + sam;
    float av[16];
    if (arow < M) {
      const float4* ap = (const float4*)(x + (size_t)arow * 64 + sak);
      float4 v0 = ap[0], v1 = ap[1], v2 = ap[2], v3 = ap[3];
      av[0] = v0.x;  av[1] = v0.y;  av[2] = v0.z;  av[3] = v0.w;
      av[4] = v1.x;  av[5] = v1.y;  av[6] = v1.z;  av[7] = v1.w;
      av[8] = v2.x;  av[9] = v2.y;  av[10] = v2.z; av[11] = v2.w;
      av[12] = v3.x; av[13] = v3.y; av[14] = v3.z; av[15] = v3.w;
    } else {
#pragma unroll
      for (int j = 0; j < 16; ++j) av[j] = 0.f;
    }
    f16x8 h0v, l0v, h1v, l1v;
#pragma unroll
    for (int j = 0; j < 8; ++j) {
      f16 hh = (f16)av[j];
      h0v[j] = hh;
      l0v[j] = (f16)(av[j] - (float)hh);
      f16 hh2 = (f16)av[8 + j];
      h1v[j] = hh2;
      l1v[j] = (f16)(av[8 + j] - (float)hh2);
    }
    *(f16x8*)&Ah[sam][sak] = h0v;
    *(f16x8*)&Ah[sam][sak + 8] = h1v;
    *(f16x8*)&Al[sam][sak] = l0v;
    *(f16x8*)&Al[sam][sak + 8] = l1v;
  }
  f32x4 acc2[2][4];
#pragma unroll
  for (int mi = 0; mi < 2; ++mi)
#pragma unroll
    for (int ni = 0; ni < 4; ++ni) acc2[mi][ni] = (f32x4){0.f, 0.f, 0.f, 0.f};

  for (int half = 0; half < 2; ++half) {
    f32x4 acc1[2][4];
#pragma unroll
    for (int mi = 0; mi < 2; ++mi)
#pragma unroll
      for (int ni = 0; ni < 4; ++ni)
        acc1[mi][ni] = (f32x4){0.f, 0.f, 0.f, 0.f};
    // phase 1: this 128-col half of h0, K=64 in 2 chunks
    for (int kc = 0; kc < 2; ++kc) {
      __syncthreads();
      {
        const f16* sh = W1h + (size_t)(half * 128 + sbn) * 64 + kc * 32 + sbk;
        const f16* sl = W1l + (size_t)(half * 128 + sbn) * 64 + kc * 32 + sbk;
        *(f16x8*)&Bh[sbn][sbk] = *(const f16x8*)sh;
        *(f16x8*)&Bh[sbn][sbk + 8] = *(const f16x8*)(sh + 8);
        *(f16x8*)&Bl[sbn][sbk] = *(const f16x8*)sl;
        *(f16x8*)&Bl[sbn][sbk + 8] = *(const f16x8*)(sl + 8);
      }
      __syncthreads();
      f16x8 ath[2], atl[2], bth[4], btl[4];
#pragma unroll
      for (int mi = 0; mi < 2; ++mi) {
        const int r = wm * 32 + mi * 16 + l15;
        ath[mi] = *(const f16x8*)&Ah[r][kc * 32 + lk8];
        atl[mi] = *(const f16x8*)&Al[r][kc * 32 + lk8];
      }
#pragma unroll
      for (int ni = 0; ni < 4; ++ni) {
        const int rn = wn * 64 + ni * 16 + l15;
        bth[ni] = *(const f16x8*)&Bh[rn][lk8];
        btl[ni] = *(const f16x8*)&Bl[rn][lk8];
      }
#pragma unroll
      for (int mi = 0; mi < 2; ++mi)
#pragma unroll
        for (int ni = 0; ni < 4; ++ni) {
          acc1[mi][ni] = __builtin_amdgcn_mfma_f32_16x16x32_f16(
              bth[ni], ath[mi], acc1[mi][ni], 0, 0, 0);
          acc1[mi][ni] = __builtin_amdgcn_mfma_f32_16x16x32_f16(
              btl[ni], ath[mi], acc1[mi][ni], 0, 0, 0);
          acc1[mi][ni] = __builtin_amdgcn_mfma_f32_16x16x32_f16(
              bth[ni], atl[mi], acc1[mi][ni], 0, 0, 0);
        }
    }
    // write H half (bias + relu + f16). Safe: all waves past kc-loop syncs.
#pragma unroll
    for (int mi = 0; mi < 2; ++mi) {
      const int m = wm * 32 + mi * 16 + l15;
#pragma unroll
      for (int ni = 0; ni < 4; ++ni) {
        const int nc = wn * 64 + ni * 16 + (lane >> 4) * 4;
        float4 bv = *(const float4*)(bb1 + half * 128 + nc);
        float b4[4] = {bv.x, bv.y, bv.z, bv.w};
        f16x4 hv;
#pragma unroll
        for (int j = 0; j < 4; ++j) {
          float v = fmaxf(acc1[mi][ni][j] + b4[j], 0.f);
          hv[j] = (f16)v;
        }
        *(f16x4*)&H[m][nc] = hv;
      }
    }
    // phase 2 partial: K chunk = half*128 .. +128 (4 x 32)
    for (int t2 = 0; t2 < 4; ++t2) {
      __syncthreads();  // H writes visible; B buffer free
      {
        const f16* sh = w2th + (size_t)sbn * 256 + half * 128 + t2 * 32 + sbk;
        const f16* sl = w2tl + (size_t)sbn * 256 + half * 128 + t2 * 32 + sbk;
        *(f16x8*)&Bh[sbn][sbk] = *(const f16x8*)sh;
        *(f16x8*)&Bh[sbn][sbk + 8] = *(const f16x8*)(sh + 8);
        *(f16x8*)&Bl[sbn][sbk] = *(const f16x8*)sl;
        *(f16x8*)&Bl[sbn][sbk + 8] = *(const f16x8*)(sl + 8);
      }
      __syncthreads();
      f16x8 ath[2], bth[4], btl[4];
#pragma unroll
      for (int mi = 0; mi < 2; ++mi)
        ath[mi] = *(const f16x8*)&H[wm * 32 + mi * 16 + l15][t2 * 32 + lk8];
#pragma unroll
      for (int ni = 0; ni < 4; ++ni) {
        const int rn = wn * 64 + ni * 16 + l15;
        bth[ni] = *(const f16x8*)&Bh[rn][lk8];
        btl[ni] = *(const f16x8*)&Bl[rn][lk8];
      }
#pragma unroll
      for (int mi = 0; mi < 2; ++mi)
#pragma unroll
        for (int ni = 0; ni < 4; ++ni) {
          acc2[mi][ni] = __builtin_amdgcn_mfma_f32_16x16x32_f16(
              bth[ni], ath[mi], acc2[mi][ni], 0, 0, 0);
          acc2[mi][ni] = __builtin_amdgcn_mfma_f32_16x16x32_f16(
              btl[ni], ath[mi], acc2[mi][ni], 0, 0, 0);
        }
    }
  }
  // epilogue: bias b2 + relu -> f16 out [M][128]
#pragma unroll
  for (int mi = 0; mi < 2; ++mi) {
    const int m = blockIdx.y * 64 + wm * 32 + mi * 16 + l15;
    if (m >= M) continue;
#pragma unroll
    for (int ni = 0; ni < 4; ++ni) {
      const int nc = wn * 64 + ni * 16 + (lane >> 4) * 4;
      float4 bv = *(const float4*)(b2 + nc);
      float b4[4] = {bv.x, bv.y, bv.z, bv.w};
      f16x4 o;
#pragma unroll
      for (int j = 0; j < 4; ++j)
        o[j] = (f16)fmaxf(acc2[mi][ni][j] + b4[j], 0.f);
      *(f16x4*)(out + (size_t)m * 128 + nc) = o;
    }
  }
}

// ---------------- MFMA GEMM core (conv + head) -----------------------------
template <int AF16, int OUT16>
__device__ __forceinline__ void gemm_core(
    const void* __restrict__ Av, const f16* __restrict__ Wth,
    const f16* __restrict__ Wtl, const float* __restrict__ bias,
    const float* __restrict__ rowscale, float* __restrict__ C,
    f16* __restrict__ C16, int M, int N, int K, int relu) {
  __shared__ f16 Ah[64][40];
  __shared__ f16 Al[AF16 ? 1 : 64][40];
  __shared__ f16 Bh[128][40], Bl[128][40];
  const int tid = threadIdx.x;
  const int wave = tid >> 6;
  const int lane = tid & 63;
  const int wm = wave & 1;
  const int wn = wave >> 1;
  const int l15 = lane & 15;
  const int lk8 = (lane >> 4) * 8;
  const int sam = tid >> 2;
  const int sak = (tid & 3) * 8;
  const int sbn = tid >> 1;
  const int sbk = (tid & 1) * 16;
  const int arow = blockIdx.y * 64 + sam;
  const f16* bhp = Wth + (size_t)(blockIdx.x * 128 + sbn) * K + sbk;
  const f16* blp = Wtl + (size_t)(blockIdx.x * 128 + sbn) * K + sbk;
  const float* aptr32 = nullptr;
  const f16* aptr16 = nullptr;
  if constexpr (AF16)
    aptr16 = (const f16*)Av + (size_t)arow * K + sak;
  else
    aptr32 = (const float*)Av + (size_t)arow * K + sak;

  f32x4 acc[2][4];
#pragma unroll
  for (int mi = 0; mi < 2; ++mi)
#pragma unroll
    for (int ni = 0; ni < 4; ++ni) acc[mi][ni] = (f32x4){0.f, 0.f, 0.f, 0.f};

  float4 pa0, pa1;
  f16x8 pa16 = {0, 0, 0, 0, 0, 0, 0, 0};
  if constexpr (AF16) {
    if (arow < M) pa16 = *(const f16x8*)aptr16;
  } else {
    if (arow < M) {
      pa0 = *(const float4*)aptr32;
      pa1 = *(const float4*)(aptr32 + 4);
    } else {
      pa0 = make_float4(0.f, 0.f, 0.f, 0.f);
      pa1 = pa0;
    }
  }
  f16x8 pbh0 = *(const f16x8*)bhp;
  f16x8 pbh1 = *(const f16x8*)(bhp + 8);
  f16x8 pbl0 = *(const f16x8*)blp;
  f16x8 pbl1 = *(const f16x8*)(blp + 8);

  const int nk = K / 32;
  for (int t = 0; t < nk; ++t) {
    if (t) __syncthreads();
    if constexpr (AF16) {
      *(f16x8*)&Ah[sam][sak] = pa16;
    } else {
      float av[8] = {pa0.x, pa0.y, pa0.z, pa0.w, pa1.x, pa1.y, pa1.z, pa1.w};
      f16x8 vh, vl;
#pragma unroll
      for (int j = 0; j < 8; ++j) {
        f16 h = (f16)av[j];
        vh[j] = h;
        vl[j] = (f16)(av[j] - (float)h);
      }
      *(f16x8*)&Ah[sam][sak] = vh;
      *(f16x8*)&Al[sam][sak] = vl;
    }
    *(f16x8*)&Bh[sbn][sbk] = pbh0;
    *(f16x8*)&Bh[sbn][sbk + 8] = pbh1;
    *(f16x8*)&Bl[sbn][sbk] = pbl0;
    *(f16x8*)&Bl[sbn][sbk + 8] = pbl1;
    __syncthreads();
    if (t + 1 < nk) {
      const int k0 = (t + 1) * 32;
      if constexpr (AF16) {
        if (arow < M) pa16 = *(const f16x8*)(aptr16 + k0);
      } else {
        if (arow < M) {
          pa0 = *(const float4*)(aptr32 + k0);
          pa1 = *(const float4*)(aptr32 + k0 + 4);
        } else {
          pa0 = make_float4(0.f, 0.f, 0.f, 0.f);
          pa1 = pa0;
        }
      }
      pbh0 = *(const f16x8*)(bhp + k0);
      pbh1 = *(const f16x8*)(bhp + k0 + 8);
      pbl0 = *(const f16x8*)(blp + k0);
      pbl1 = *(const f16x8*)(blp + k0 + 8);
    }
    f16x8 ath[2], atl[2];
#pragma unroll
    for (int mi = 0; mi < 2; ++mi) {
      const int r = wm * 32 + mi * 16 + l15;
      ath[mi] = *(const f16x8*)&Ah[r][lk8];
      if constexpr (!AF16) atl[mi] = *(const f16x8*)&Al[r][lk8];
    }
    f16x8 bth[4], btl[4];
#pragma unroll
    for (int ni = 0; ni < 4; ++ni) {
      const int r = wn * 64 + ni * 16 + l15;
      bth[ni] = *(const f16x8*)&Bh[r][lk8];
      btl[ni] = *(const f16x8*)&Bl[r][lk8];
    }
#pragma unroll
    for (int mi = 0; mi < 2; ++mi)
#pragma unroll
      for (int ni = 0; ni < 4; ++ni) {
        acc[mi][ni] = __builtin_amdgcn_mfma_f32_16x16x32_f16(
            bth[ni], ath[mi], acc[mi][ni], 0, 0, 0);
        acc[mi][ni] = __builtin_amdgcn_mfma_f32_16x16x32_f16(
            btl[ni], ath[mi], acc[mi][ni], 0, 0, 0);
        if constexpr (!AF16)
          acc[mi][ni] = __builtin_amdgcn_mfma_f32_16x16x32_f16(
              bth[ni], atl[mi], acc[mi][ni], 0, 0, 0);
      }
  }

#pragma unroll
  for (int mi = 0; mi < 2; ++mi) {
    const int m = blockIdx.y * 64 + wm * 32 + mi * 16 + l15;
    if (m >= M) continue;
    float s = 1.f;
    if (OUT16 && rowscale) s = rowscale[m];
#pragma unroll
    for (int ni = 0; ni < 4; ++ni) {
      const int nb = blockIdx.x * 128 + wn * 64 + ni * 16 + (lane >> 4) * 4;
      float bv[4] = {0.f, 0.f, 0.f, 0.f};
      if (bias) {
        float4 b4 = *(const float4*)(bias + nb);
        bv[0] = b4.x; bv[1] = b4.y; bv[2] = b4.z; bv[3] = b4.w;
      }
      if constexpr (OUT16) {
        f16x4 h;
#pragma unroll
        for (int j = 0; j < 4; ++j) {
          float vj = acc[mi][ni][j] * s + bv[j];
          if (relu) vj = fmaxf(vj, 0.f);
          h[j] = (f16)vj;
        }
        *(f16x4*)(C16 + (size_t)m * N + nb) = h;
      } else {
        float4 v;
        v.x = acc[mi][ni][0] + bv[0];
        v.y = acc[mi][ni][1] + bv[1];
        v.z = acc[mi][ni][2] + bv[2];
        v.w = acc[mi][ni][3] + bv[3];
        if (relu) {
          v.x = fmaxf(v.x, 0.f);
          v.y = fmaxf(v.y, 0.f);
          v.z = fmaxf(v.z, 0.f);
          v.w = fmaxf(v.w, 0.f);
        }
        *(float4*)(C + (size_t)m * N + nb) = v;
      }
    }
  }
}

__global__ __launch_bounds__(256) void gemm_a16_f16o(
    const f16* __restrict__ A0, const f16* __restrict__ A1,
    const f16* __restrict__ Wth, const f16* __restrict__ Wtl,
    const float* __restrict__ bias, const float* __restrict__ rowscale,
    f16* __restrict__ C0, f16* __restrict__ C1, int M, int N, int K,
    int relu) {
  const int z = blockIdx.z;
  gemm_core<1, 1>(z ? A1 : A0, Wth, Wtl, bias,
                  rowscale ? rowscale + (size_t)z * M : nullptr, nullptr,
                  z ? C1 : C0, M, N, K, relu);
}

__global__ __launch_bounds__(256) void gemm_a32_f32o(
    const float* __restrict__ A, const f16* __restrict__ Wth,
    const f16* __restrict__ Wtl, const float* __restrict__ bias,
    float* __restrict__ C, int M, int N, int K, int relu) {
  gemm_core<0, 0>(A, Wth, Wtl, bias, nullptr, C, nullptr, M, N, K, relu);
}

// ============== CSR build: deterministic two-level counting sort ===========
__global__ __launch_bounds__(256) void hist_k(
    const int* __restrict__ ei0, const int* __restrict__ ei1,
    int* __restrict__ ghist, int e, int nbkt, int nc) {
  const int z = blockIdx.z;
  const int c = blockIdx.x;
  const int* dst = (z ? ei1 : ei0) + e;
  int* gh = ghist + (size_t)z * nbkt * nc;
  __shared__ int h[256];
  h[threadIdx.x] = 0;
  __syncthreads();
  const int i0 = c * CH;
  const int i1 = min(e, i0 + CH);
  for (int i = i0 + threadIdx.x; i < i1; i += 256)
    atomicAdd(&h[__builtin_nontemporal_load(dst + i) >> BSH], 1);
  __syncthreads();
  if (threadIdx.x < nbkt) gh[threadIdx.x * nc + c] = h[threadIdx.x];
}

__global__ __launch_bounds__(1024) void scanh_k(int* __restrict__ ghist,
                                                int nbkt, int nc) {
  const int tot = nbkt * nc;
  int* gh = ghist + (size_t)blockIdx.z * tot;
  __shared__ int part[1024];
  const int t = threadIdx.x;
  const int per = (tot + 1023) / 1024;
  const int base = t * per;
  int s = 0;
  for (int j = 0; j < per; ++j) {
    int i = base + j;
    if (i < tot) s += gh[i];
  }
  part[t] = s;
  __syncthreads();
  for (int off = 1; off < 1024; off <<= 1) {
    int v = (t >= off) ? part[t - off] : 0;
    __syncthreads();
    part[t] += v;
    __syncthreads();
  }
  int run = part[t] - s;  // exclusive prefix
  for (int j = 0; j < per; ++j) {
    int i = base + j;
    if (i < tot) {
      int v = gh[i];
      gh[i] = run;
      run += v;
    }
  }
}

__global__ __launch_bounds__(256) void scatter_k(
    const int* __restrict__ ei0, const int* __restrict__ ei1,
    const int* __restrict__ ghist, u32* __restrict__ ebkt, int e, int nbkt,
    int nc) {
  const int z = blockIdx.z;
  const int c = blockIdx.x;
  const int* src = z ? ei1 : ei0;
  const int* dst = src + e;
  const int* gh = ghist + (size_t)z * nbkt * nc;
  u32* eb = ebkt + (size_t)z * e;
  __shared__ int cur[256];
  if (threadIdx.x < nbkt) cur[threadIdx.x] = gh[threadIdx.x * nc + c];
  __syncthreads();
  const int i0 = c * CH;
  const int i1 = min(e, i0 + CH);
  for (int i = i0 + threadIdx.x; i < i1; i += 256) {
    int s = __builtin_nontemporal_load(src + i);
    int d = __builtin_nontemporal_load(dst + i);
    int pos = atomicAdd(&cur[d >> BSH], 1);
    eb[pos] = (u32)s | ((u32)(d & 255) << 16);
  }
}

__global__ __launch_bounds__(256) void build_k(
    const int* __restrict__ ghist, const u32* __restrict__ ebkt,
    u16* __restrict__ esrc, int* __restrict__ rowstart,
    float* __restrict__ dinv, int e, int n, int nbkt, int nc) {
  const int z = blockIdx.z;
  const int b = blockIdx.x;
  const int* gh = ghist + (size_t)z * nbkt * nc;
  const u32* eb = ebkt + (size_t)z * e;
  u16* es = esrc + (size_t)z * e;
  int* rs = rowstart + (size_t)z * (n + 1);
  float* dv = dinv + (size_t)z * n;
  const int tid = threadIdx.x;
  const int bstart = gh[b * nc];
  const int bend = (b + 1 < nbkt) ? gh[(b + 1) * nc] : e;
  const int cnt = bend - bstart;
  __shared__ int h[256], ts[256], cur[256];
  __shared__ u16 stage[12288];
  h[tid] = 0;
  __syncthreads();
  for (int i = bstart + tid; i < bend; i += 256)
    atomicAdd(&h[eb[i] >> 16], 1);
  __syncthreads();
  int deg = h[tid];
  ts[tid] = deg;
  __syncthreads();
  for (int off = 1; off < 256; off <<= 1) {
    int v = (tid >= off) ? ts[tid - off] : 0;
    __syncthreads();
    ts[tid] += v;
    __syncthreads();
  }
  const int excl = ts[tid] - deg;
  const int vglob = (b << BSH) + tid;
  if (vglob <= n) rs[vglob] = bstart + excl;
  if (vglob < n) dv[vglob] = rsqrtf((float)(deg + 1));
  cur[tid] = excl;
  __syncthreads();
  if (cnt <= 12288) {
    for (int i = bstart + tid; i < bend; i += 256) {
      u32 p = eb[i];
      int pos = atomicAdd(&cur[p >> 16], 1);
      stage[pos] = (u16)(p & 0xffff);
    }
    __syncthreads();
    for (int j = tid; j < cnt; j += 256) es[bstart + j] = stage[j];
  } else {
    for (int i = bstart + tid; i < bend; i += 256) {
      u32 p = eb[i];
      int pos = atomicAdd(&cur[p >> 16], 1);
      es[bstart + pos] = (u16)(p & 0xffff);
    }
  }
}

// ---------------- gather: half-split (round 14), x8-unrolled ---------------
// 1D grid; xcd = blk & 7: tower = xcd>>2, half = (xcd>>1)&1, sub = xcd&1.
// 8 threads/node x f16x8 (64 features per half, 128B = one line).
__global__ __launch_bounds__(256) void gather8_k(
    const int* __restrict__ rowstart, const u16* __restrict__ esrc,
    const f16* __restrict__ xw16, const float* __restrict__ dinv,
    const float* __restrict__ bias, f16* __restrict__ out0,
    f16* __restrict__ out1, int n, int e, int bpt) {
  const int blk = blockIdx.x;
  const int xcd = blk & 7;
  const int z = xcd >> 2;
  const int half = (xcd >> 1) & 1;
  const int idx = (blk >> 3) * 2 + (xcd & 1);
  if (idx >= bpt) return;
  const int* rs = rowstart + (size_t)z * (n + 1);
  const u16* es = esrc + (size_t)z * e;
  const f16x8* x8 = (const f16x8*)(xw16 + (size_t)z * n * 128);
  const float* dv = dinv + (size_t)z * n;
  f16* out = z ? out1 : out0;
  int gid = idx * 256 + threadIdx.x;
  int v = gid >> 3;
  if (v >= n) return;
  int q = gid & 7;
  const int fo = half * 8 + q;
  f16x8 sv = x8[(size_t)v * 16 + fo];
  float acc[8];
#pragma unroll
  for (int j = 0; j < 8; ++j) acc[j] = (float)sv[j];
  const int s0 = rs[v], s1 = rs[v + 1];
  int ed = s0;
  for (; ed + 8 <= s1; ed += 8) {
    int si[8];
#pragma unroll
    for (int u = 0; u < 8; ++u) si[u] = es[ed + u];
    f16x8 t[8];
#pragma unroll
    for (int u = 0; u < 8; ++u) t[u] = x8[(size_t)si[u] * 16 + fo];
#pragma unroll
    for (int j = 0; j < 8; ++j)
      acc[j] += (((float)t[0][j] + (float)t[1][j]) +
                 ((float)t[2][j] + (float)t[3][j])) +
                (((float)t[4][j] + (float)t[5][j]) +
                 ((float)t[6][j] + (float)t[7][j]));
  }
  for (; ed + 4 <= s1; ed += 4) {
    int sa = es[ed], sb = es[ed + 1], sc = es[ed + 2], sd = es[ed + 3];
    f16x8 ta = x8[(size_t)sa * 16 + fo];
    f16x8 tb = x8[(size_t)sb * 16 + fo];
    f16x8 tc = x8[(size_t)sc * 16 + fo];
    f16x8 td = x8[(size_t)sd * 16 + fo];
#pragma unroll
    for (int j = 0; j < 8; ++j)
      acc[j] += ((float)ta[j] + (float)tb[j]) + ((float)tc[j] + (float)td[j]);
  }
  for (; ed < s1; ++ed) {
    f16x8 t = x8[(size_t)es[ed] * 16 + fo];
#pragma unroll
    for (int j = 0; j < 8; ++j) acc[j] += (float)t[j];
  }
  float d = dv[v];
  float4 b0 = *(const float4*)(bias + fo * 8);
  float4 b1 = *(const float4*)(bias + fo * 8 + 4);
  float bb[8] = {b0.x, b0.y, b0.z, b0.w, b1.x, b1.y, b1.z, b1.w};
  f16x8 o;
#pragma unroll
  for (int j = 0; j < 8; ++j) o[j] = (f16)fmaxf(acc[j] * d + bb[j], 0.f);
  *(f16x8*)(out + (size_t)v * 128 + fo * 8) = o;
}

// ---------------- pool: segmented mean (f16 in, f32 out), z = tower --------
__global__ __launch_bounds__(256) void bstart_k(const int* __restrict__ b0,
                                                const int* __restrict__ b1,
                                                int* __restrict__ bstart,
                                                int n, int nb) {
  const int z = blockIdx.z;
  const int* batch = z ? b1 : b0;
  int* bst = bstart + (size_t)z * (nb + 1);
  int b = blockIdx.x * 256 + threadIdx.x;
  if (b > nb) return;
  int lo = 0, hi = n;
  while (lo < hi) {
    int mid = (lo + hi) >> 1;
    if (batch[mid] < b) lo = mid + 1; else hi = mid;
  }
  bst[b] = lo;
}

__global__ __launch_bounds__(128) void pool_seg_k(
    const f16* __restrict__ h0, const f16* __restrict__ h1,
    const int* __restrict__ bstart, float* __restrict__ cat, int nb) {
  const int z = blockIdx.z;
  const f16* h = z ? h1 : h0;
  const int* bst = bstart + (size_t)z * (nb + 1);
  int b = blockIdx.x;
  int s = bst[b], e = bst[b + 1];
  int f = threadIdx.x;
  float acc = 0.f;
  for (int v = s; v < e; ++v) acc += (float)h[(size_t)v * 128 + f];
  float c = fmaxf((float)(e - s), 1.f);
  cat[(size_t)b * 256 + z * 128 + f] = acc / c;
}

// ---------------- final: out[r] = z2[r,:]@W5 + b5 --------------------------
__global__ __launch_bounds__(256) void final_k(const float* __restrict__ z2,
                                               const float* __restrict__ W5,
                                               const float* __restrict__ b5,
                                               float* __restrict__ out,
                                               int rows) {
  int r = blockIdx.x * 256 + threadIdx.x;
  if (r >= rows) return;
  float acc = b5[0];
#pragma unroll
  for (int k = 0; k < 128; ++k) acc += z2[(size_t)r * 128 + k] * W5[k];
  out[r] = acc;
}

// ---------------------------------------------------------------------------
extern "C" void kernel_launch(void* const* d_in, const int* in_sizes, int n_in,
                              void* d_out, int out_size, void* d_ws,
                              size_t ws_size, hipStream_t stream) {
  const float* x0 = (const float*)d_in[0];
  const float* x1 = (const float*)d_in[3];
  const int* ei0 = (const int*)d_in[1];
  const int* ei1 = (const int*)d_in[4];
  const int* ba0 = (const int*)d_in[2];
  const int* ba1 = (const int*)d_in[5];
  const float* gamma = (const float*)d_in[6];
  const float* beta = (const float*)d_in[7];
  const float* W1 = (const float*)d_in[8];
  const float* b1 = (const float*)d_in[9];
  const float* W2 = (const float*)d_in[10];
  const float* b2 = (const float*)d_in[11];
  const float* Wc[3] = {(const float*)d_in[12], (const float*)d_in[14],
                        (const float*)d_in[16]};
  const float* bc[3] = {(const float*)d_in[13], (const float*)d_in[15],
                        (const float*)d_in[17]};
  const float* W3 = (const float*)d_in[18];
  const float* b3 = (const float*)d_in[19];
  const float* W4 = (const float*)d_in[20];
  const float* b4 = (const float*)d_in[21];
  const float* W5 = (const float*)d_in[22];
  const float* b5 = (const float*)d_in[23];
  float* out = (float*)d_out;

  const int N = in_sizes[0] / 64;  // 50000
  const int E = in_sizes[1] / 2;   // 600000
  const int B = out_size;          // 512
  const int NBKT = (N + 255) >> BSH;  // 196
  const int NC = (E + CH - 1) / CH;   // 74

  // ---- workspace layout ----
  f16* fp = (f16*)d_ws;
  f16* hA16 = fp; fp += (size_t)2 * N * 128;   // activation ping
  f16* hB16 = fp; fp += (size_t)2 * N * 128;   // activation pong
  f16* xw16 = fp; fp += (size_t)2 * N * 128;   // conv GEMM out (dinv-scaled)
  float* dinv = (float*)fp;                    // 2*N
  u16* esrc = (u16*)(dinv + (size_t)2 * N);    // 2*E
  u32* ebkt = (u32*)(esrc + (size_t)2 * E);    // 2*E u32
  int* ghist = (int*)(ebkt + (size_t)2 * E);   // 2*NBKT*NC
  int* rowstart = ghist + (size_t)2 * NBKT * NC;  // 2*(N+1)
  int* bstart = rowstart + (size_t)2 * (N + 1);   // 2*(B+1)
  float* bnsum = (float*)(bstart + 2 * (B + 1));  // 128
  float* bnsq = bnsum + 128;                      // 128
  float* b1f = bnsq + 128;                        // 512
  float* catb = b1f + 512;                        // B*256
  float* z1 = catb + (size_t)B * 256;             // B*256
  float* z2 = z1 + (size_t)B * 256;               // B*128
  f16* wtp = (f16*)(((uintptr_t)(z2 + (size_t)B * 128) + 63) &
                    ~(uintptr_t)63);
  f16* w1t_h = wtp; wtp += 2 * 16384;  // per tower [256][64]
  f16* w1t_l = wtp; wtp += 2 * 16384;
  f16* w2t_h = wtp; wtp += 32768;      // [128][256]
  f16* w2t_l = wtp; wtp += 32768;
  f16* wct_h[3]; f16* wct_l[3];
  for (int c = 0; c < 3; ++c) {
    wct_h[c] = wtp; wtp += 16384;      // [128][128]
    wct_l[c] = wtp; wtp += 16384;
  }
  f16* w3t_h = wtp; wtp += 65536;      // [256][256]
  f16* w3t_l = wtp; wtp += 65536;
  f16* w4t_h = wtp; wtp += 32768;      // [128][256]
  f16* w4t_l = wtp; wtp += 32768;
  size_t need = (size_t)((char*)wtp - (char*)d_ws);
  if (ws_size < need) return;

  f16* hA_[2] = {hA16, hA16 + (size_t)N * 128};
  f16* hB_[2] = {hB16, hB16 + (size_t)N * 128};

  const int nb_g8 = (N * 8 + 255) / 256;     // gather blocks per (tower,half)
  const int g_grid = ((nb_g8 + 1) / 2) * 8;  // XCD-decoded 1D grid
  const int gby = (N + 63) / 64;             // 782

  hipMemsetAsync(bnsum, 0, 256 * sizeof(float), stream);

  // ---- shared weights: transpose+split, ONE dispatch ----
  wtrans_all_k<<<dim3(4, 64, 6), 256, 0, stream>>>(
      W2, Wc[0], Wc[1], Wc[2], W3, W4, w2t_h, w2t_l, wct_h[0], wct_l[0],
      wct_h[1], wct_l[1], wct_h[2], wct_l[2], w3t_h, w3t_l, w4t_h, w4t_l);

  // ---- BN -> folded W1 (per tower, transposed/split written directly) ----
  bn_stats_k<<<dim3(256, 1, 2), 256, 0, stream>>>(x0, x1, bnsum, bnsq, N);
  bn_fold_k<<<2, 256, 0, stream>>>(bnsum, bnsq, gamma, beta, W1, b1, w1t_h,
                                   w1t_l, b1f, 1.0f / (float)N);

  // ---- fused GEMM1+GEMM2 ----
  fused12_k<<<dim3(1, gby, 2), 256, 0, stream>>>(
      x0, x1, w1t_h, w1t_l, b1f, w2t_h, w2t_l, b2, hA_[0], hA_[1], N);

  // ---- CSR build: two-level counting sort (deterministic) ----
  hist_k<<<dim3(NC, 1, 2), 256, 0, stream>>>(ei0, ei1, ghist, E, NBKT, NC);
  scanh_k<<<dim3(1, 1, 2), 1024, 0, stream>>>(ghist, NBKT, NC);
  scatter_k<<<dim3(NC, 1, 2), 256, 0, stream>>>(ei0, ei1, ghist, ebkt, E,
                                                NBKT, NC);
  build_k<<<dim3(NBKT, 1, 2), 256, 0, stream>>>(ghist, ebkt, esrc, rowstart,
                                                dinv, E, N, NBKT, NC);
  bstart_k<<<dim3((B + 256) / 256, 1, 2), 256, 0, stream>>>(ba0, ba1, bstart,
                                                            N, B);

  // ---- 3 conv layers: GEMM(f16, dinv-scaled) + gather (f16 out) ----
  f16* cin[3][2] = {{hA_[0], hA_[1]}, {hB_[0], hB_[1]}, {hA_[0], hA_[1]}};
  f16* cout[3][2] = {{hB_[0], hB_[1]}, {hA_[0], hA_[1]}, {hB_[0], hB_[1]}};
  for (int c = 0; c < 3; ++c) {
    gemm_a16_f16o<<<dim3(1, gby, 2), 256, 0, stream>>>(
        cin[c][0], cin[c][1], wct_h[c], wct_l[c], nullptr, dinv, xw16,
        xw16 + (size_t)N * 128, N, 128, 128, 0);
    gather8_k<<<dim3(g_grid, 1, 1), 256, 0, stream>>>(
        rowstart, esrc, xw16, dinv, bc[c], cout[c][0], cout[c][1], N, E,
        nb_g8);
  }

  // ---- pool (both towers) ----
  pool_seg_k<<<dim3(B, 1, 2), 128, 0, stream>>>(hB_[0], hB_[1], bstart, catb,
                                                B);

  // ---- head MLP (f32) ----
  gemm_a32_f32o<<<dim3(2, (B + 63) / 64, 1), 256, 0, stream>>>(
      catb, w3t_h, w3t_l, b3, z1, B, 256, 256, 1);
  gemm_a32_f32o<<<dim3(1, (B + 63) / 64, 1), 256, 0, stream>>>(
      z1, w4t_h, w4t_l, b4, z2, B, 128, 256, 1);
  final_k<<<(B + 255) / 256, 256, 0, stream>>>(z2, W5, b5, out, B);
}